// Round 11
// baseline (1031.088 us; speedup 1.0000x reference)
//
#include <hip/hip_runtime.h>

#define HID 128
#define EMB 64
// dynamic LDS layout (bytes): spre16 131072 | h1 1280 | h2 1280 | tok 2048 |
// sfin 512 | xn 512 | sc 48  -> 136752, padded
#define SMEM_BYTES 136832

__device__ __forceinline__ float fast_tanh(float x) {   // 1 - 2/(exp(2x)+1)
    float e = __expf(2.f * x);
    return 1.f - __fdividef(2.f, e + 1.f);
}

// pin a float4 (prevents rematerialization) — R9-proven recipe
#define OPQ(v) asm volatile("" : "+v"(v.x), "+v"(v.y), "+v"(v.z), "+v"(v.w))

// ---- exact-codegen MAC: one VOP2 each (R3/R9-proven)
#define FMAC(a, h, w) asm("v_fmac_f32 %0, %1, %2" : "+v"(a) : "v"(h), "v"(w))
#define VMUL(a, h, w) asm("v_mul_f32 %0, %1, %2" : "=v"(a) : "v"(h), "v"(w))
#define MAC4(hc, wa, wb, wcc, wd) \
    FMAC(s0, hc, wa); FMAC(s1, hc, wb); FMAC(s2, hc, wcc); FMAC(s3, hc, wd)

// ---- fused DPP butterfly reduce (R3/R9-proven)
#define RED_STAGE(ctrl) \
    "v_add_f32_dpp %0, %0, %0 " ctrl " row_mask:0xf bank_mask:0xf\n\t" \
    "v_add_f32_dpp %1, %1, %1 " ctrl " row_mask:0xf bank_mask:0xf\n\t" \
    "v_add_f32_dpp %2, %2, %2 " ctrl " row_mask:0xf bank_mask:0xf\n\t" \
    "v_add_f32_dpp %3, %3, %3 " ctrl " row_mask:0xf bank_mask:0xf\n\t"
#define REDUCE_L1 asm("s_nop 1\n\t" \
    RED_STAGE("quad_perm:[1,0,3,2]") \
    RED_STAGE("quad_perm:[2,3,0,1]") \
    RED_STAGE("row_half_mirror") \
    : "+v"(s0), "+v"(s1), "+v"(s2), "+v"(s3))
#define REDUCE_L2 asm("s_nop 1\n\t" \
    RED_STAGE("quad_perm:[1,0,3,2]") \
    RED_STAGE("quad_perm:[2,3,0,1]") \
    RED_STAGE("row_half_mirror") \
    RED_STAGE("row_mirror") \
    : "+v"(s0), "+v"(s1), "+v"(s2), "+v"(s3))

// block-wide sum for 768 threads (12 waves); pass 0 from non-contributing lanes
__device__ inline float bsum768(float v, volatile float* sc, int tid) {
#pragma unroll
    for (int off = 32; off > 0; off >>= 1) v += __shfl_down(v, off, 64);
    __syncthreads();
    if ((tid & 63) == 0) sc[tid >> 6] = v;
    __syncthreads();
    float s = 0.f;
#pragma unroll
    for (int k = 0; k < 12; ++k) s += sc[k];
    return s;
}

// ---------------- single fused kernel: embed/input-GEMM prologue (per-block,
// only this block's 512 tokens) + R9-champion two-layer recurrence + epilogue.
// Prologue: lane owns Wih1 rows {lane, lane+64} in regs; wave wv computes
// t = wv, wv+12, ...: pre[t] = Wih1 @ emb[tok[t]] + bih1 + bhh1, stored fp16
// in LDS (128 KB; we run 1 block/CU so LDS was idle capacity).
// Scan (R9-exact math): waves 0-3 (L1): h1_t = tanh(pre[t] + Whh1 @ h1_{t-1});
// waves 4-11 (L2): h2_{t-1} = tanh(b2 + Wih2@h1_{t-1} + Whh2@h2_{t-2})  (lag-1).
__global__ __launch_bounds__(768)
__attribute__((amdgpu_waves_per_eu(3)))
void k_rnn_fused(
    const int* __restrict__ x, const float* __restrict__ emb,
    const float* __restrict__ Wih1, const float* __restrict__ bih1,
    const float* __restrict__ bhh1, const float* __restrict__ Whh1,
    const float* __restrict__ Wih2, const float* __restrict__ bih2,
    const float* __restrict__ bhh2, const float* __restrict__ Whh2,
    const float* __restrict__ ln_g, const float* __restrict__ ln_b,
    const float* __restrict__ projW, const float* __restrict__ proj_b,
    const float* __restrict__ on_g, const float* __restrict__ on_b,
    float* __restrict__ out)
{
    extern __shared__ __align__(16) char smem[];
    _Float16* spre16 = (_Float16*)smem;               // [512][128] fp16 pre-values
    float* h1b  = (float*)(smem + 131072);            // [2][160] (i at (i>>4)*20+(i&15))
    float* h2b  = (float*)(smem + 132352);            // [2][160]
    int*   tok  = (int*)(smem + 133632);              // [512]
    float* sfin = (float*)(smem + 135680);            // [128]
    float* xn   = (float*)(smem + 136192);            // [128]
    float* sc   = (float*)(smem + 136704);            // [12]

    const int bb   = blockIdx.x;
    const int tid  = threadIdx.x;
    const int w    = tid >> 6;
    const int lane = tid & 63;
    const bool L1  = (w < 4);
    const int  e   = lane & 7;                     // column-eighth
    const int  m   = L1 ? 0 : ((lane >> 3) & 1);   // L2: 0 = Wih2 (h1), 1 = Whh2 (h2)
    const int  rg  = L1 ? (lane >> 3) : (lane >> 4);
    const int  rowbase = L1 ? (32 * w + rg) : (16 * (w - 4) + rg);
    const int  rstep   = L1 ? 8 : 4;
    const float* wmat  = L1 ? Whh1 : (m ? Whh2 : Wih2);

    // publisher role: lanes e<4 (for L2 only m==0 half) write row rowbase+(e&3)*rstep
    const bool wr_en = L1 ? (e < 4) : (m == 0 && e < 4);
    const int  wrow  = rowbase + (e & 3) * rstep;
    const int  wword = ((wrow >> 4) * 20) + (wrow & 15);
    const float b2w  = (!L1 && wr_en) ? (bih2[wrow] + bhh2[wrow]) : 0.f;
    const bool pfe   = L1 && wr_en;                // this lane reads pre values

    if (tid < 160) { h1b[tid] = 0.f; h2b[tid] = 0.f; }   // zero parity 0
    if (tid < 512) tok[tid] = x[bb * 512 + tid];
    __syncthreads();                    // tok + h init visible

    // ---- prologue: pre[t] = Wih1 @ emb[tok[t]] + bih1 + bhh1 -> spre16 (fp16)
    {
        const float4* wAp = (const float4*)(Wih1 + (size_t)lane * EMB);
        const float4* wBp = (const float4*)(Wih1 + (size_t)(lane + 64) * EMB);
        float4 wa[16], wb[16];
#pragma unroll
        for (int k = 0; k < 16; ++k) { wa[k] = wAp[k]; wb[k] = wBp[k]; }
        const float bA = bih1[lane] + bhh1[lane];
        const float bB = bih1[lane + 64] + bhh1[lane + 64];
        for (int t = w; t < 512; t += 12) {
            const float4* ep = (const float4*)(emb + (size_t)tok[t] * EMB);
            float a0 = bA, a1 = 0.f, b0 = bB, b1 = 0.f;
#pragma unroll
            for (int k = 0; k < 16; ++k) {
                float4 ev = ep[k];
                a0 = fmaf(ev.x, wa[k].x, a0); a1 = fmaf(ev.y, wa[k].y, a1);
                a0 = fmaf(ev.z, wa[k].z, a0); a1 = fmaf(ev.w, wa[k].w, a1);
                b0 = fmaf(ev.x, wb[k].x, b0); b1 = fmaf(ev.y, wb[k].y, b1);
                b0 = fmaf(ev.z, wb[k].z, b0); b1 = fmaf(ev.w, wb[k].w, b1);
            }
            spre16[t * HID + lane]      = (_Float16)(a0 + a1);
            spre16[t * HID + lane + 64] = (_Float16)(b0 + b1);
        }
    }
    __syncthreads();                    // spre16 complete

    // ---- recurrence weights: 4 rows x 16 cols (16 float4 = 64 floats / lane)
    const float4* wr0 = (const float4*)(wmat + (size_t)(rowbase            ) * HID + e * 16);
    const float4* wr1 = (const float4*)(wmat + (size_t)(rowbase +     rstep) * HID + e * 16);
    const float4* wr2 = (const float4*)(wmat + (size_t)(rowbase + 2 * rstep) * HID + e * 16);
    const float4* wr3 = (const float4*)(wmat + (size_t)(rowbase + 3 * rstep) * HID + e * 16);
    float4 w0 = wr0[0], w1 = wr0[1], w2  = wr0[2], w3  = wr0[3],
           w4 = wr1[0], w5 = wr1[1], w6  = wr1[2], w7  = wr1[3],
           w8 = wr2[0], w9 = wr2[1], w10 = wr2[2], w11 = wr2[3],
           w12= wr3[0], w13= wr3[1], w14 = wr3[2], w15 = wr3[3];
    OPQ(w0);OPQ(w1);OPQ(w2);OPQ(w3);OPQ(w4);OPQ(w5);OPQ(w6);OPQ(w7);
    OPQ(w8);OPQ(w9);OPQ(w10);OPQ(w11);OPQ(w12);OPQ(w13);OPQ(w14);OPQ(w15);

    // parity-resolved pointers (even t reads [0] writes [1]; odd t flips)
    const float* srcb = (L1 || m == 0) ? h1b : h2b;
    const float4* rp0 = (const float4*)(srcb + e * 20);
    const float4* rp1 = (const float4*)(srcb + 160 + e * 20);
    float* dstb = L1 ? h1b : h2b;
    float* wp_e = dstb + 160 + wword;   // even step writes parity 1
    float* wp_o = dstb + wword;         // odd step writes parity 0

    // pre-value register ring (2-step prefetch): pA even steps, pB odd steps
    float pA = 0.f, pB = 0.f;
    if (pfe) {
        pA = (float)spre16[wrow];
        pB = (float)spre16[HID + wrow];
    }

    auto do_step = [&](int t, float& pslot, int tn, const float4* rp, float* wpt) {
        const float pv = pslot;
        float4 hv0 = rp[0], hv1 = rp[1], hv2 = rp[2], hv3 = rp[3];
        float s0, s1, s2, s3;
        VMUL(s0, hv0.x, w0.x); VMUL(s1, hv0.x, w4.x);
        VMUL(s2, hv0.x, w8.x); VMUL(s3, hv0.x, w12.x);
        MAC4(hv0.y, w0.y, w4.y, w8.y, w12.y);
        MAC4(hv0.z, w0.z, w4.z, w8.z, w12.z);
        MAC4(hv0.w, w0.w, w4.w, w8.w, w12.w);
        MAC4(hv1.x, w1.x, w5.x, w9.x, w13.x);
        MAC4(hv1.y, w1.y, w5.y, w9.y, w13.y);
        MAC4(hv1.z, w1.z, w5.z, w9.z, w13.z);
        MAC4(hv1.w, w1.w, w5.w, w9.w, w13.w);
        MAC4(hv2.x, w2.x, w6.x, w10.x, w14.x);
        MAC4(hv2.y, w2.y, w6.y, w10.y, w14.y);
        MAC4(hv2.z, w2.z, w6.z, w10.z, w14.z);
        MAC4(hv2.w, w2.w, w6.w, w10.w, w14.w);
        MAC4(hv3.x, w3.x, w7.x, w11.x, w15.x);
        MAC4(hv3.y, w3.y, w7.y, w11.y, w15.y);
        MAC4(hv3.z, w3.z, w7.z, w11.z, w15.z);
        MAC4(hv3.w, w3.w, w7.w, w11.w, w15.w);
        if (L1) { REDUCE_L1; } else { REDUCE_L2; }
        if (pfe) pslot = (float)spre16[tn * HID + wrow];   // prefetch 2 ahead (LDS)
        if (wr_en) {
            float ta = (e & 1) ? s1 : s0;
            float tb = (e & 1) ? s3 : s2;
            float v  = (e & 2) ? tb : ta;
            if (L1) *wpt = fast_tanh(pv + v);
            else    *wpt = (t > 0) ? fast_tanh(b2w + v) : 0.f;   // h2_{-1} = 0
        }
        __syncthreads();
    };

#pragma unroll 1
    for (int t = 0; t < 512; t += 2) {
        do_step(t,     pA, (t + 2 < 512) ? t + 2 : 511, rp0, wp_e);
        do_step(t + 1, pB, (t + 3 < 512) ? t + 3 : 511, rp1, wp_o);
    }

    // drain: h2_511 = tanh(b2 + Wih2@h1_511 + Whh2@h2_510); both live at parity 0.
    // L1 lanes compute a dead value into h1 parity 1 (harmless).
    {
        float* wpD = L1 ? wp_e : &sfin[wrow];
        do_step(512, pA, 511, rp0, wpD);
    }

    // ---- epilogue: LN -> proj+tanh -> LN (R3/R9-proven)
    const int i = tid & 127;
    float hn = (tid < 128) ? sfin[i] : 0.f;
    float s1v = bsum768(hn, sc, tid);
    float s2v = bsum768(hn * hn, sc, tid);
    float mu = s1v * (1.f / 128.f);
    float var = s2v * (1.f / 128.f) - mu * mu;
    __syncthreads();
    if (tid < 128) xn[i] = (hn - mu) * rsqrtf(var + 1e-5f) * ln_g[i] + ln_b[i];
    __syncthreads();
    float pv = 0.f;
    if (tid < 128) {
        float a0 = proj_b[i], a1 = 0, a2 = 0, a3 = 0;
        const float4* hp = (const float4*)xn;
        const float4* pr = (const float4*)(projW + (size_t)i * HID);
#pragma unroll
        for (int k = 0; k < HID / 4; ++k) {
            float4 u = pr[k];
            float4 hv = hp[k];
            a0 = fmaf(hv.x, u.x, a0); a1 = fmaf(hv.y, u.y, a1);
            a2 = fmaf(hv.z, u.z, a2); a3 = fmaf(hv.w, u.w, a3);
        }
        pv = tanhf((a0 + a1) + (a2 + a3));
    }
    float t1 = bsum768(pv, sc, tid);
    float t2 = bsum768(pv * pv, sc, tid);
    float mu2 = t1 * (1.f / 128.f);
    float var2 = t2 * (1.f / 128.f) - mu2 * mu2;
    if (tid < 128)
        out[(size_t)bb * HID + i] = (pv - mu2) * rsqrtf(var2 + 1e-5f) * on_g[i] + on_b[i];
}

extern "C" void kernel_launch(void* const* d_in, const int* in_sizes, int n_in,
                              void* d_out, int out_size, void* d_ws, size_t ws_size,
                              hipStream_t stream)
{
    const int*   x     = (const int*)  d_in[0];
    const float* emb   = (const float*)d_in[1];
    const float* Wih1  = (const float*)d_in[2];
    const float* bih1  = (const float*)d_in[3];
    const float* Whh1  = (const float*)d_in[4];
    const float* bhh1  = (const float*)d_in[5];
    const float* Wih2  = (const float*)d_in[6];
    const float* bih2  = (const float*)d_in[7];
    const float* Whh2  = (const float*)d_in[8];
    const float* bhh2  = (const float*)d_in[9];
    const float* ln_g  = (const float*)d_in[10];
    const float* ln_b  = (const float*)d_in[11];
    const float* projW = (const float*)d_in[12];
    const float* projb = (const float*)d_in[13];
    const float* on_g  = (const float*)d_in[14];
    const float* on_b  = (const float*)d_in[15];

    // opt in to >64 KB dynamic LDS (gfx950 has 160 KB/CU); immediate host-side
    // call, not a stream op — safe under graph capture.
    hipFuncSetAttribute(reinterpret_cast<const void*>(k_rnn_fused),
                        hipFuncAttributeMaxDynamicSharedMemorySize, SMEM_BYTES);

    k_rnn_fused<<<256, 768, SMEM_BYTES, stream>>>(
        x, emb, Wih1, bih1, bhh1, Whh1, Wih2, bih2, bhh2, Whh2,
        ln_g, ln_b, projW, projb, on_g, on_b, (float*)d_out);
}

// Round 12
// 448.679 us; speedup vs baseline: 2.2981x; 2.2981x over previous
//
#include <hip/hip_runtime.h>

#define HID 128
#define EMB 64
#define VOCAB 120000

typedef float f32x2 __attribute__((ext_vector_type(2)));
typedef float f32x4v __attribute__((ext_vector_type(4)));

__device__ __forceinline__ float fast_tanh(float x) {   // 1 - 2/(exp(2x)+1)
    float e = __expf(2.f * x);
    return 1.f - __fdividef(2.f, e + 1.f);
}

// pin a 64-bit pair / keep value live (prevents rematerialization)
#define PIN2(v) asm volatile("" : "+v"(v))

// packed fp32 MAC: 2 FLOPs per instruction (VOP3P; R1-proven exact + functional)
#define PKFMA(d, a, b) asm("v_pk_fma_f32 %0, %1, %2, %0" : "+v"(d) : "v"(a), "v"(b))
#define PKMUL(d, a, b) asm("v_pk_mul_f32 %0, %1, %2" : "=v"(d) : "v"(a), "v"(b))

// sub-register pair extraction (zero-cost: adjacent elements of an aligned quad)
#define SPLLO(q) __builtin_shufflevector(q, q, 0, 1)
#define SPLHI(q) __builtin_shufflevector(q, q, 2, 3)

// declare + load + pin one weight row (16 cols = 8 f32x2 pairs) from ptr
#define LOADROW(P, ptr) \
    f32x2 P##0, P##1, P##2, P##3, P##4, P##5, P##6, P##7; \
    { const f32x4v* _q = (const f32x4v*)(ptr); \
      f32x4v _q0 = _q[0], _q1 = _q[1], _q2 = _q[2], _q3 = _q[3]; \
      P##0 = SPLLO(_q0); P##1 = SPLHI(_q0); P##2 = SPLLO(_q1); P##3 = SPLHI(_q1); \
      P##4 = SPLLO(_q2); P##5 = SPLHI(_q2); P##6 = SPLLO(_q3); P##7 = SPLHI(_q3); } \
    PIN2(P##0); PIN2(P##1); PIN2(P##2); PIN2(P##3); \
    PIN2(P##4); PIN2(P##5); PIN2(P##6); PIN2(P##7);

// one h-pair against all 4 row accumulators
#define PK4(hp, idx) \
    PKFMA(a0, hp, WA##idx); PKFMA(a1, hp, WB##idx); \
    PKFMA(a2, hp, WC##idx); PKFMA(a3, hp, WD##idx);

// ---- fused DPP butterfly reduce (R3/R9-proven)
#define RED_STAGE(ctrl) \
    "v_add_f32_dpp %0, %0, %0 " ctrl " row_mask:0xf bank_mask:0xf\n\t" \
    "v_add_f32_dpp %1, %1, %1 " ctrl " row_mask:0xf bank_mask:0xf\n\t" \
    "v_add_f32_dpp %2, %2, %2 " ctrl " row_mask:0xf bank_mask:0xf\n\t" \
    "v_add_f32_dpp %3, %3, %3 " ctrl " row_mask:0xf bank_mask:0xf\n\t"
#define REDUCE_L1 asm("s_nop 1\n\t" \
    RED_STAGE("quad_perm:[1,0,3,2]") \
    RED_STAGE("quad_perm:[2,3,0,1]") \
    RED_STAGE("row_half_mirror") \
    : "+v"(s0), "+v"(s1), "+v"(s2), "+v"(s3))
#define REDUCE_L2 asm("s_nop 1\n\t" \
    RED_STAGE("quad_perm:[1,0,3,2]") \
    RED_STAGE("quad_perm:[2,3,0,1]") \
    RED_STAGE("row_half_mirror") \
    RED_STAGE("row_mirror") \
    : "+v"(s0), "+v"(s1), "+v"(s2), "+v"(s3))

// ---------------- kernel 1: W1E[v] = Wih1 @ emb[v] + bih1 + bhh1  (R9-proven)
__global__ __launch_bounds__(256)
__attribute__((amdgpu_waves_per_eu(1, 2)))
void k_w1e(
    const float* __restrict__ emb, const float* __restrict__ Wih1,
    const float* __restrict__ bih1, const float* __restrict__ bhh1,
    float* __restrict__ W1E)
{
    __shared__ float sA[32][128];
    __shared__ float sW[32][132];
    const int tid = threadIdx.x;
    const int base = blockIdx.x * 128;
    const int tx = tid & 15, ty = tid >> 4;
    const int ox = tx * 8, py = ty * 8;
    const int pl = tid & 127, half = tid >> 7;
    const int rv = min(base + pl, VOCAB - 1);   // clamped read row (tail block)
    float acc[8][8];
#pragma unroll
    for (int p = 0; p < 8; ++p)
#pragma unroll
        for (int o = 0; o < 8; ++o) acc[p][o] = 0.f;
    const float4* ws = (const float4*)(Wih1 + (size_t)pl * EMB + half * 16);
    const float4* as = (const float4*)(emb + (size_t)rv * EMB + half * 16);
    float4 qw[2][4], qe[2][4];
#pragma unroll
    for (int kc = 0; kc < 2; ++kc)
#pragma unroll
        for (int k = 0; k < 4; ++k) {
            qw[kc][k] = ws[kc * 8 + k];
            qe[kc][k] = as[kc * 8 + k];
        }
    for (int kc = 0; kc < 2; ++kc) {
        {
            const int jb = half * 16;
#pragma unroll
            for (int k = 0; k < 4; ++k) {
                float4 q = qw[kc][k], e = qe[kc][k];
                sW[jb + 4*k + 0][pl] = q.x; sW[jb + 4*k + 1][pl] = q.y;
                sW[jb + 4*k + 2][pl] = q.z; sW[jb + 4*k + 3][pl] = q.w;
                sA[jb + 4*k + 0][pl] = e.x; sA[jb + 4*k + 1][pl] = e.y;
                sA[jb + 4*k + 2][pl] = e.z; sA[jb + 4*k + 3][pl] = e.w;
            }
        }
        __syncthreads();
#pragma unroll 4
        for (int j = 0; j < 32; ++j) {
            float4 a0 = *(const float4*)&sA[j][py];
            float4 a1 = *(const float4*)&sA[j][py + 4];
            float4 b0 = *(const float4*)&sW[j][ox];
            float4 b1 = *(const float4*)&sW[j][ox + 4];
            float av[8] = {a0.x,a0.y,a0.z,a0.w,a1.x,a1.y,a1.z,a1.w};
            float bv[8] = {b0.x,b0.y,b0.z,b0.w,b1.x,b1.y,b1.z,b1.w};
#pragma unroll
            for (int p = 0; p < 8; ++p)
#pragma unroll
                for (int o = 0; o < 8; ++o)
                    acc[p][o] = fmaf(av[p], bv[o], acc[p][o]);
        }
        __syncthreads();
    }
    float bo[8];
#pragma unroll
    for (int o = 0; o < 8; ++o) bo[o] = bih1[ox + o] + bhh1[ox + o];
#pragma unroll
    for (int p = 0; p < 8; ++p) {
        const int vout = base + py + p;
        if (vout < VOCAB) {
            float* cp = W1E + (size_t)vout * HID + ox;
            *(float4*)cp       = make_float4(acc[p][0]+bo[0], acc[p][1]+bo[1], acc[p][2]+bo[2], acc[p][3]+bo[3]);
            *(float4*)(cp + 4) = make_float4(acc[p][4]+bo[4], acc[p][5]+bo[5], acc[p][6]+bo[6], acc[p][7]+bo[7]);
        }
    }
}

// block-wide sum for 768 threads (12 waves); pass 0 from non-contributing lanes
__device__ inline float bsum768(float v, volatile float* sc, int tid) {
#pragma unroll
    for (int off = 32; off > 0; off >>= 1) v += __shfl_down(v, off, 64);
    __syncthreads();
    if ((tid & 63) == 0) sc[tid >> 6] = v;
    __syncthreads();
    float s = 0.f;
#pragma unroll
    for (int k = 0; k < 12; ++k) s += sc[k];
    return s;
}

// ---------------- kernel 2: fused two-layer recurrence — R9-champion structure,
// MAC core re-expressed as v_pk_fma_f32 pairs (4 pk_mul + 28 pk_fma + 4 adds
// replace 64 v_fmac_f32; VOP3P = 2 fp32 FLOP/instr, exact — R1-proven).
// waves 0-3 (L1): h1_t = tanh(W1E[tok[t]][r] + Whh1 @ h1_{t-1})
// waves 4-11(L2): h2_{t-1} = tanh(b2 + Wih2@h1_{t-1} + Whh2@h2_{t-2})  (lag-1)
__global__ __launch_bounds__(768)
__attribute__((amdgpu_waves_per_eu(3)))
void k_rnn_fused(
    const int* __restrict__ x, const float* __restrict__ W1E,
    const float* __restrict__ Whh1,
    const float* __restrict__ Wih2, const float* __restrict__ bih2,
    const float* __restrict__ bhh2, const float* __restrict__ Whh2,
    const float* __restrict__ ln_g, const float* __restrict__ ln_b,
    const float* __restrict__ projW, const float* __restrict__ proj_b,
    const float* __restrict__ on_g, const float* __restrict__ on_b,
    float* __restrict__ out)
{
    // h layout: value i at word (i>>4)*20 + (i&15) -> conflict-free ds_read_b128.
    __shared__ __align__(16) float h1[2][160];
    __shared__ __align__(16) float h2[2][160];
    __shared__ int   tok[512];
    __shared__ float sfin[HID];
    __shared__ float xn[HID];
    __shared__ float sc[12];

    const int bb   = blockIdx.x;
    const int tid  = threadIdx.x;
    const int w    = tid >> 6;
    const int lane = tid & 63;
    const bool L1  = (w < 4);
    const int  e   = lane & 7;                     // column-eighth
    const int  m   = L1 ? 0 : ((lane >> 3) & 1);   // L2: 0 = Wih2 (h1), 1 = Whh2 (h2)
    const int  rg  = L1 ? (lane >> 3) : (lane >> 4);
    const int  rowbase = L1 ? (32 * w + rg) : (16 * (w - 4) + rg);
    const int  rstep   = L1 ? 8 : 4;
    const float* wmat  = L1 ? Whh1 : (m ? Whh2 : Wih2);

    // ---- 4 rows x 16 cols of weights as 32 pinned f32x2 pairs (64 regs/lane)
    LOADROW(WA, wmat + (size_t)(rowbase            ) * HID + e * 16)   // s0-row
    LOADROW(WB, wmat + (size_t)(rowbase +     rstep) * HID + e * 16)   // s1-row
    LOADROW(WC, wmat + (size_t)(rowbase + 2 * rstep) * HID + e * 16)   // s2-row
    LOADROW(WD, wmat + (size_t)(rowbase + 3 * rstep) * HID + e * 16)   // s3-row

    // publisher role: lanes e<4 (for L2 only m==0 half) write row rowbase+(e&3)*rstep
    const bool wr_en = L1 ? (e < 4) : (m == 0 && e < 4);
    const int  wrow  = rowbase + (e & 3) * rstep;
    const int  wword = ((wrow >> 4) * 20) + (wrow & 15);
    const float b2w  = (!L1 && wr_en) ? (bih2[wrow] + bhh2[wrow]) : 0.f;
    const bool pfe   = L1 && wr_en;                // this lane gathers pre values

    if (tid < 160) { h1[0][tid] = 0.f; h2[0][tid] = 0.f; }
    if (tid < 512) tok[tid] = x[bb * 512 + tid];

    // parity-resolved pointers (even t reads [0] writes [1]; odd t flips)
    const float* srcb = (L1 || m == 0) ? &h1[0][0] : &h2[0][0];
    const f32x4v* rp0 = (const f32x4v*)(srcb + e * 20);
    const f32x4v* rp1 = (const f32x4v*)(srcb + 160 + e * 20);
    float* dstb = L1 ? &h1[0][0] : &h2[0][0];
    float* wp_e = dstb + 160 + wword;   // even step writes parity 1
    float* wp_o = dstb + wword;         // odd step writes parity 0

    __syncthreads();                    // h init + tok visible

    // pre-value register ring (2-step prefetch): pA even steps, pB odd steps
    float pA = 0.f, pB = 0.f;
    if (pfe) {
        pA = W1E[(size_t)tok[0] * HID + wrow];
        pB = W1E[(size_t)tok[1] * HID + wrow];
    }

    auto do_step = [&](int t, float& pslot, int tn, const f32x4v* rp, float* wpt) {
        const float pv = pslot;
        f32x4v hv0 = rp[0], hv1 = rp[1], hv2 = rp[2], hv3 = rp[3];
        f32x2 h0 = SPLLO(hv0), h1p = SPLHI(hv0), h2p = SPLLO(hv1), h3 = SPLHI(hv1),
              h4 = SPLLO(hv2), h5 = SPLHI(hv2), h6 = SPLLO(hv3), h7 = SPLHI(hv3);
        f32x2 a0, a1, a2, a3;
        PKMUL(a0, h0, WA0); PKMUL(a1, h0, WB0); PKMUL(a2, h0, WC0); PKMUL(a3, h0, WD0);
        PK4(h1p, 1) PK4(h2p, 2) PK4(h3, 3)
        PK4(h4, 4) PK4(h5, 5) PK4(h6, 6) PK4(h7, 7)
        float s0 = a0.x + a0.y, s1 = a1.x + a1.y, s2 = a2.x + a2.y, s3 = a3.x + a3.y;
        if (L1) { REDUCE_L1; } else { REDUCE_L2; }
        if (pfe) pslot = W1E[(size_t)tok[tn] * HID + wrow];   // prefetch 2 ahead
        if (wr_en) {
            float ta = (e & 1) ? s1 : s0;
            float tb = (e & 1) ? s3 : s2;
            float v  = (e & 2) ? tb : ta;
            if (L1) *wpt = fast_tanh(pv + v);
            else    *wpt = (t > 0) ? fast_tanh(b2w + v) : 0.f;   // h2_{-1} = 0
        }
        __syncthreads();
    };

#pragma unroll 1
    for (int t = 0; t < 512; t += 2) {
        do_step(t,     pA, (t + 2 < 512) ? t + 2 : 511, rp0, wp_e);
        do_step(t + 1, pB, (t + 3 < 512) ? t + 3 : 511, rp1, wp_o);
    }

    // drain: h2_511 = tanh(b2 + Wih2@h1_511 + Whh2@h2_510); both live at parity 0.
    // L1 lanes compute a dead value into h1[1] (harmless).
    {
        float* wpD = L1 ? wp_e : &sfin[wrow];
        do_step(512, pA, 511, rp0, wpD);
    }

    // ---- epilogue: LN -> proj+tanh -> LN (R3/R9-proven)
    const int i = tid & 127;
    float hn = (tid < 128) ? sfin[i] : 0.f;
    float s1v = bsum768(hn, sc, tid);
    float s2v = bsum768(hn * hn, sc, tid);
    float mu = s1v * (1.f / 128.f);
    float var = s2v * (1.f / 128.f) - mu * mu;
    __syncthreads();
    if (tid < 128) xn[i] = (hn - mu) * rsqrtf(var + 1e-5f) * ln_g[i] + ln_b[i];
    __syncthreads();
    float pv = 0.f;
    if (tid < 128) {
        float a0 = proj_b[i], a1 = 0, a2 = 0, a3 = 0;
        const float4* hp = (const float4*)xn;
        const float4* pr = (const float4*)(projW + (size_t)i * HID);
#pragma unroll
        for (int k = 0; k < HID / 4; ++k) {
            float4 u = pr[k];
            float4 hv = hp[k];
            a0 = fmaf(hv.x, u.x, a0); a1 = fmaf(hv.y, u.y, a1);
            a2 = fmaf(hv.z, u.z, a2); a3 = fmaf(hv.w, u.w, a3);
        }
        pv = tanhf((a0 + a1) + (a2 + a3));
    }
    float t1 = bsum768(pv, sc, tid);
    float t2 = bsum768(pv * pv, sc, tid);
    float mu2 = t1 * (1.f / 128.f);
    float var2 = t2 * (1.f / 128.f) - mu2 * mu2;
    if (tid < 128)
        out[(size_t)bb * HID + i] = (pv - mu2) * rsqrtf(var2 + 1e-5f) * on_g[i] + on_b[i];
}

extern "C" void kernel_launch(void* const* d_in, const int* in_sizes, int n_in,
                              void* d_out, int out_size, void* d_ws, size_t ws_size,
                              hipStream_t stream)
{
    const int*   x     = (const int*)  d_in[0];
    const float* emb   = (const float*)d_in[1];
    const float* Wih1  = (const float*)d_in[2];
    const float* bih1  = (const float*)d_in[3];
    const float* Whh1  = (const float*)d_in[4];
    const float* bhh1  = (const float*)d_in[5];
    const float* Wih2  = (const float*)d_in[6];
    const float* bih2  = (const float*)d_in[7];
    const float* Whh2  = (const float*)d_in[8];
    const float* bhh2  = (const float*)d_in[9];
    const float* ln_g  = (const float*)d_in[10];
    const float* ln_b  = (const float*)d_in[11];
    const float* projW = (const float*)d_in[12];
    const float* projb = (const float*)d_in[13];
    const float* on_g  = (const float*)d_in[14];
    const float* on_b  = (const float*)d_in[15];

    float* W1E = (float*)d_ws;   // [VOCAB][128] fp32 = 61.4 MB (ws is 64 MiB)

    k_w1e<<<(VOCAB + 127) / 128, 256, 0, stream>>>(emb, Wih1, bih1, bhh1, W1E);
    k_rnn_fused<<<256, 768, 0, stream>>>(x, W1E, Whh1, Wih2, bih2, bhh2, Whh2,
                                         ln_g, ln_b, projW, projb, on_g, on_b,
                                         (float*)d_out);
}